// Round 2
// baseline (487.077 us; speedup 1.0000x reference)
//
#include <hip/hip_runtime.h>

// RGCN bipartite, FP32 in/out. Round 13 (9 dispatches):
//   - REVERT round-12 fusions (they cut gather TLP: 10000 waves -> 5000 and
//     added a 16-row barrier tail; non-mega time +21us). Back to round-11
//     agg_bel / gemmHG / gemm structure (349us verified).
//   - NEW: degree counters padded to 1 per 128B line (stride CS=32 ints).
//     Theory: hist's 1.2M device-scope atomics serialize per-LINE (c_bd/c_is
//     packed = 480 same-line atomics/line from 8 XCDs ~= 48us). Padding makes
//     per-line == per-address contention (30-way max). Ranks/scales bitwise
//     identical -- only the stride changes.
//   - scan: single-pass per-thread-segment version (from r12, verified).

#define NA 50000
#define NB 10000
#define NE 300000
#define GB 625      // mega: gemm blocks
#define HB 1172     // mega: hist blocks
#define PB 64       // mega: pack blocks
#define CB 300      // mega: cvt blocks
#define CS 32       // counter stride (ints) -> 128B per counter

typedef unsigned short u16;
typedef unsigned int u32;
typedef __attribute__((ext_vector_type(8))) short short8;
typedef __attribute__((ext_vector_type(4))) float f32x4;
typedef __attribute__((ext_vector_type(2))) float f32x2;
typedef __attribute__((ext_vector_type(4))) unsigned short u16x4;
typedef __attribute__((ext_vector_type(4))) int i32x4;

__device__ __forceinline__ float bf2f(u16 h){
  union { u32 u; float f; } x; x.u = ((u32)h) << 16; return x.f;
}
__device__ __forceinline__ u16 f2bf(float f){
  union { float f; u32 u; } x; x.f = f;
  u32 r = (x.u + 0x7FFFu + ((x.u >> 16) & 1u)) >> 16;   // RNE
  return (u16)r;
}

// pack element t of the global layout [W1b 64k][W1i 64k][W2b 32k][W2i 32k]
__device__ __forceinline__ void pack_elem(int t,
    const float* __restrict__ W1b, const float* __restrict__ W1i,
    const float* __restrict__ W2b, const float* __restrict__ W2i,
    u16* __restrict__ pwh, u16* __restrict__ pwl){
  const float* W; int N; int tt;
  if (t < 65536)       { W = W1b; N = 256; tt = t; }
  else if (t < 131072) { W = W1i; N = 256; tt = t - 65536; }
  else if (t < 163840) { W = W2b; N = 128; tt = t - 131072; }
  else                 { W = W2i; N = 128; tt = t - 163840; }
  int j = tt & 7, lane = (tt >> 3) & 63, tile = tt >> 9;
  int nT = N >> 4;
  int nt = tile % nT, kt = tile / nT;
  int k = kt * 32 + ((lane >> 4) << 3) + j;
  int n = nt * 16 + (lane & 15);
  float v = W[k * N + n];
  u16 hi = f2bf(v);
  pwh[t] = hi;
  pwl[t] = f2bf(v - bf2f(hi));
}

// ====== pre: zero padded counters (int4) + pack W1i (G1 gemm operand) ======
__global__ __launch_bounds__(256) void pre_kernel(
    int* __restrict__ z, int nz4, const float* __restrict__ W1i,
    u16* __restrict__ pwh, u16* __restrict__ pwl){
  int g = blockIdx.x * blockDim.x + threadIdx.x;
  int s = gridDim.x * blockDim.x;
  i32x4* z4 = (i32x4*)z;
  i32x4 zero = {0, 0, 0, 0};
  for (int i = g; i < nz4; i += s) __builtin_nontemporal_store(zero, z4 + i);
  for (int t = g; t < 65536; t += s)
    pack_elem(65536 + t, nullptr, W1i, nullptr, nullptr, pwh, pwl);
}

// ================= gemm device fn (single live acc, no spills) =============
__device__ __forceinline__ void gemm_dev(int blk, const float* __restrict__ A,
                                         const u16* __restrict__ PWH,
                                         const u16* __restrict__ PWL,
                                         const float* __restrict__ bias,
                                         const float* __restrict__ rs,
                                         float* __restrict__ Cf,
                                         u16* __restrict__ C16,
                                         int M, int nT, int wpsShift,
                                         int doRelu, int ldC, int colOff){
  int wave = blk * 4 + (threadIdx.x >> 6);
  int lane = threadIdx.x & 63;
  int strips = M >> 4;
  int strip = wave >> wpsShift;
  if (strip >= strips) return;
  int slice = wave & ((1 << wpsShift) - 1);
  int ntPer = nT >> wpsShift;
  int ntStart = slice * ntPer;
  int r16 = lane & 15, quad = lane >> 4;
  int m0 = strip << 4;
  const float* aBase = A + (size_t)(m0 + r16) * 256 + quad * 8;
  short8 ah[8], al[8];
#pragma unroll
  for (int kt = 0; kt < 8; ++kt){
    float4 p0 = *(const float4*)(aBase + kt * 32);
    float4 p1 = *(const float4*)(aBase + kt * 32 + 4);
    float v[8] = {p0.x, p0.y, p0.z, p0.w, p1.x, p1.y, p1.z, p1.w};
    short8 h, l;
#pragma unroll
    for (int j = 0; j < 8; ++j){
      u16 hb = f2bf(v[j]);
      h[j] = (short)hb;
      l[j] = (short)f2bf(v[j] - bf2f(hb));
    }
    ah[kt] = h; al[kt] = l;
  }
  float rscale[4];
#pragma unroll
  for (int r = 0; r < 4; ++r) rscale[r] = rs ? rs[m0 + quad * 4 + r] : 1.f;
  for (int nt = ntStart; nt < ntStart + ntPer; ++nt){
    f32x4 acc = {0.f, 0.f, 0.f, 0.f};
    const u16* bh = PWH + ((size_t)nt * 64 + lane) * 8;
    const u16* bl = PWL + ((size_t)nt * 64 + lane) * 8;
#pragma unroll
    for (int kt = 0; kt < 8; ++kt){
      short8 wh = *(const short8*)(bh + (size_t)kt * nT * 512);
      short8 wl = *(const short8*)(bl + (size_t)kt * nT * 512);
      acc = __builtin_amdgcn_mfma_f32_16x16x32_bf16(ah[kt], wh, acc, 0, 0, 0);
      acc = __builtin_amdgcn_mfma_f32_16x16x32_bf16(al[kt], wh, acc, 0, 0, 0);
      acc = __builtin_amdgcn_mfma_f32_16x16x32_bf16(ah[kt], wl, acc, 0, 0, 0);
    }
    int col = nt * 16 + r16;
    float bv = bias ? bias[col] : 0.f;
#pragma unroll
    for (int r = 0; r < 4; ++r){
      float v = acc[r] * rscale[r] + bv;
      if (doRelu) v = fmaxf(v, 0.f);
      size_t o = (size_t)(m0 + quad * 4 + r) * ldC + colOff + col;
      if (C16) __builtin_nontemporal_store(f2bf(v), C16 + o);
      else     __builtin_nontemporal_store(v, Cf + o);
    }
  }
}

// ====== MEGA: [G1 gemm | hist+ranks | pack rest | cvt x_a] block-split =====
__global__ __launch_bounds__(256) void mega_kernel(
    const float* __restrict__ xb,
    const u16* __restrict__ WH1i, const u16* __restrict__ WL1i,
    u16* __restrict__ G12,
    const int* __restrict__ bs, const int* __restrict__ bd,
    const int* __restrict__ isc, const int* __restrict__ idt,
    int* __restrict__ c_bs, int* __restrict__ c_bd,
    int* __restrict__ c_is, int* __restrict__ c_id,
    int* __restrict__ rank_bel, int* __restrict__ rank_inc,
    const float* __restrict__ W1b, const float* __restrict__ W2b,
    const float* __restrict__ W2i,
    u16* __restrict__ pwh, u16* __restrict__ pwl,
    const float* __restrict__ xa, u16* __restrict__ xa16){
  int blk = blockIdx.x;
  if (blk < GB){
    // G1 = x_b @ W1i (UNSCALED; s_oi applied at gather) -> G12 cols [0,256)
    gemm_dev(blk, xb, WH1i, WL1i, nullptr, nullptr,
             nullptr, G12, NB, 16, 2, 0, 384, 0);
  } else if (blk < GB + HB){
    int g = (blk - GB) * blockDim.x + threadIdx.x;
    int s = HB * blockDim.x;
    for (int e = g; e < NE; e += s){
      atomicAdd(&c_bs[bs[e] * CS], 1);
      rank_bel[e] = atomicAdd(&c_bd[bd[e] * CS], 1);
      atomicAdd(&c_is[isc[e] * CS], 1);
      rank_inc[e] = atomicAdd(&c_id[idt[e] * CS], 1);
    }
  } else if (blk < GB + HB + PB){
    int g = (blk - GB - HB) * blockDim.x + threadIdx.x;
    int s = PB * blockDim.x;
    for (int v = g; v < 131072; v += s){
      int t = v < 65536 ? v : v + 65536;   // skip W1i range (packed in pre)
      pack_elem(t, W1b, nullptr, W2b, W2i, pwh, pwl);
    }
  } else {
    int g = ((blk - GB - HB - PB) * blockDim.x + threadIdx.x) * 4;
    int s = CB * blockDim.x * 4;
    for (int i = g; i < NA * 256; i += s){
      float4 v = *(const float4*)(xa + i);
      u16x4 o;
      o.x = f2bf(v.x); o.y = f2bf(v.y); o.z = f2bf(v.z); o.w = f2bf(v.w);
      __builtin_nontemporal_store(o, (u16x4*)(xa16 + i));
    }
  }
}

// ============ scan (blocks 0,1; single pass) + scales (blocks 2..) =========
__global__ __launch_bounds__(1024) void scan_scales_kernel(
    const int* __restrict__ c_bs, const int* __restrict__ c_bd,
    const int* __restrict__ c_is, const int* __restrict__ c_id,
    int* __restrict__ off_bel, int* __restrict__ off_inc,
    float* __restrict__ s_ob, float* __restrict__ s_ib,
    float* __restrict__ s_oi, float* __restrict__ s_ii){
  if (blockIdx.x >= 2){
    int g = (blockIdx.x - 2) * blockDim.x + threadIdx.x;
    int s = (gridDim.x - 2) * blockDim.x;
    for (int i = g; i < NA; i += s){
      int a = c_bs[i * CS]; s_ob[i] = rsqrtf((float)(a > 1 ? a : 1));
      int b = c_id[i * CS]; s_ii[i] = rsqrtf((float)(b > 1 ? b : 1));
      if (i < NB){
        int c = c_bd[i * CS]; s_ib[i] = rsqrtf((float)(c > 1 ? c : 1));
        int d = c_is[i * CS]; s_oi[i] = rsqrtf((float)(d > 1 ? d : 1));
      }
    }
    return;
  }
  const int* cnt; int* off; int n;
  if (blockIdx.x == 0){ cnt = c_bd; off = off_bel; n = NB; }
  else                { cnt = c_id; off = off_inc; n = NA; }
  __shared__ int wsum[16];
  int tid = threadIdx.x, lane = tid & 63, wid = tid >> 6;
  int seg = (n + 1023) >> 10;
  int i0 = tid * seg;
  int lim = i0 + seg; if (lim > n) lim = n;
  int sum = 0;
  for (int i = i0; i < lim; ++i) sum += cnt[i * CS];
  int x = sum;
#pragma unroll
  for (int d = 1; d < 64; d <<= 1){ int t = __shfl_up(x, d, 64); if (lane >= d) x += t; }
  if (lane == 63) wsum[wid] = x;
  __syncthreads();
  if (wid == 0){
    int ws = (lane < 16) ? wsum[lane] : 0;
#pragma unroll
    for (int d = 1; d < 16; d <<= 1){ int t = __shfl_up(ws, d, 64); if (lane >= d) ws += t; }
    if (lane < 16) wsum[lane] = ws;
  }
  __syncthreads();
  int run = (wid ? wsum[wid - 1] : 0) + (x - sum);
  for (int i = i0; i < lim; ++i){ off[i] = run; run += cnt[i * CS]; }
  if (tid == 0) off[n] = wsum[15];
}

// ============ CSR fill: NO atomics (slot = off[dst] + rank[e]) =============
__global__ __launch_bounds__(256) void fill_kernel(
    const int* __restrict__ bs, const int* __restrict__ bd,
    const int* __restrict__ isc, const int* __restrict__ idt,
    const int* __restrict__ rank_bel, const int* __restrict__ rank_inc,
    const int* __restrict__ off_bel, const int* __restrict__ off_inc,
    int* __restrict__ csr_bel, int* __restrict__ csr_inc){
  int g = blockIdx.x * blockDim.x + threadIdx.x;
  int s = gridDim.x * blockDim.x;
  for (int e = g; e < NE; e += s){
    csr_bel[off_bel[bd[e]] + rank_bel[e]] = bs[e];
    csr_inc[off_inc[idt[e]] + rank_inc[e]] = isc[e];
  }
}

// ================= bel aggregation (dst = B, 10000 rows) ===================
__global__ __launch_bounds__(256) void agg_bel_kernel(
    const u16* __restrict__ X, const float* __restrict__ ss,
    const int* __restrict__ off, const int* __restrict__ csr,
    float* __restrict__ Pf, int nDst){
  int wave = blockIdx.x * 4 + (threadIdx.x >> 6);
  int lane = threadIdx.x & 63;
  if (wave >= nDst) return;
  int b0 = off[wave], b1 = off[wave + 1];
  int deg = b1 - b0;
  int part = lane >> 5;
  int cl = lane & 31;
  int c = cl * 8;
  float acc[8];
#pragma unroll
  for (int q = 0; q < 8; ++q) acc[q] = 0.f;
  int idx = 0; float sc = 0.f;
  if (lane < deg){
    idx = csr[b0 + lane];
    sc = ss ? ss[idx] : 1.f;
  }
  int lim = deg < 64 ? deg : 64;
  for (int u = 0; u < lim; u += 8){
    const u16* addr[4]; float w[4];
#pragma unroll
    for (int k = 0; k < 4; ++k){
      int e = u + k * 2 + part;
      int t = e < lim ? e : 0;
      int s0 = __shfl(idx, t, 64);
      float c0 = __shfl(sc, t, 64);
      w[k] = e < lim ? c0 : 0.f;
      addr[k] = X + (size_t)s0 * 256 + c;
    }
    short8 v[4];
#pragma unroll
    for (int k = 0; k < 4; ++k) v[k] = *(const short8*)addr[k];
#pragma unroll
    for (int k = 0; k < 4; ++k)
#pragma unroll
      for (int q = 0; q < 8; ++q) acc[q] += bf2f((u16)v[k][q]) * w[k];
  }
  for (int j = b0 + 64 + part; j < b1; j += 2){
    int s0 = csr[j];
    float c0 = ss ? ss[s0] : 1.f;
    short8 v0 = *(const short8*)(X + (size_t)s0 * 256 + c);
#pragma unroll
    for (int q = 0; q < 8; ++q) acc[q] += bf2f((u16)v0[q]) * c0;
  }
#pragma unroll
  for (int q = 0; q < 8; ++q) acc[q] += __shfl_xor(acc[q], 32, 64);
  if (part == 0){
    f32x4 f0 = {acc[0], acc[1], acc[2], acc[3]};
    f32x4 f1 = {acc[4], acc[5], acc[6], acc[7]};
    __builtin_nontemporal_store(f0, (f32x4*)(Pf + (size_t)wave * 256 + c));
    __builtin_nontemporal_store(f1, (f32x4*)(Pf + (size_t)wave * 256 + c + 4));
  }
}

// ====== gemmHG: H_b strip -> LDS fp32 -> G2 gemm (UNSCALED), per strip =====
__global__ __launch_bounds__(256) void gemmHG_kernel(
    const float* __restrict__ Pb,
    const u16* __restrict__ WH1b, const u16* __restrict__ WL1b,
    const float* __restrict__ b1b, const float* __restrict__ s_ib,
    const u16* __restrict__ WH2i, const u16* __restrict__ WL2i,
    u16* __restrict__ G12){
  __shared__ float Hs[16][260];
  int w = threadIdx.x >> 6;
  int lane = threadIdx.x & 63;
  int r16 = lane & 15, quad = lane >> 4;
  int m0 = blockIdx.x << 4;
  // ---- phase 1: H_b = relu((P_b@W1b)*s_ib + b1b) into LDS ----
  const float* aBase = Pb + (size_t)(m0 + r16) * 256 + quad * 8;
  short8 ah[8], al[8];
#pragma unroll
  for (int kt = 0; kt < 8; ++kt){
    float4 p0 = *(const float4*)(aBase + kt * 32);
    float4 p1 = *(const float4*)(aBase + kt * 32 + 4);
    float v[8] = {p0.x, p0.y, p0.z, p0.w, p1.x, p1.y, p1.z, p1.w};
    short8 h, l;
#pragma unroll
    for (int j = 0; j < 8; ++j){
      u16 hb = f2bf(v[j]);
      h[j] = (short)hb;
      l[j] = (short)f2bf(v[j] - bf2f(hb));
    }
    ah[kt] = h; al[kt] = l;
  }
  float rs1[4];
#pragma unroll
  for (int r = 0; r < 4; ++r) rs1[r] = s_ib[m0 + quad * 4 + r];
  for (int nt = w * 4; nt < w * 4 + 4; ++nt){
    f32x4 acc = {0.f, 0.f, 0.f, 0.f};
    const u16* bh = WH1b + ((size_t)nt * 64 + lane) * 8;
    const u16* bl = WL1b + ((size_t)nt * 64 + lane) * 8;
#pragma unroll
    for (int kt = 0; kt < 8; ++kt){
      short8 wh = *(const short8*)(bh + (size_t)kt * 16 * 512);
      short8 wl = *(const short8*)(bl + (size_t)kt * 16 * 512);
      acc = __builtin_amdgcn_mfma_f32_16x16x32_bf16(ah[kt], wh, acc, 0, 0, 0);
      acc = __builtin_amdgcn_mfma_f32_16x16x32_bf16(al[kt], wh, acc, 0, 0, 0);
      acc = __builtin_amdgcn_mfma_f32_16x16x32_bf16(ah[kt], wl, acc, 0, 0, 0);
    }
    int col = nt * 16 + r16;
    float bv = b1b[col];
#pragma unroll
    for (int r = 0; r < 4; ++r)
      Hs[quad * 4 + r][col] = fmaxf(acc[r] * rs1[r] + bv, 0.f);
  }
  __syncthreads();
  // ---- phase 2: G2 = H_b @ W2i (UNSCALED) -> G12 cols [256,384) ----
  short8 ah2[8], al2[8];
#pragma unroll
  for (int kt = 0; kt < 8; ++kt){
    float4 p0 = *(const float4*)&Hs[r16][kt * 32 + quad * 8];
    float4 p1 = *(const float4*)&Hs[r16][kt * 32 + quad * 8 + 4];
    float v[8] = {p0.x, p0.y, p0.z, p0.w, p1.x, p1.y, p1.z, p1.w};
    short8 h, l;
#pragma unroll
    for (int j = 0; j < 8; ++j){
      u16 hb = f2bf(v[j]);
      h[j] = (short)hb;
      l[j] = (short)f2bf(v[j] - bf2f(hb));
    }
    ah2[kt] = h; al2[kt] = l;
  }
  for (int nt = w * 2; nt < w * 2 + 2; ++nt){
    f32x4 acc = {0.f, 0.f, 0.f, 0.f};
    const u16* bh = WH2i + ((size_t)nt * 64 + lane) * 8;
    const u16* bl = WL2i + ((size_t)nt * 64 + lane) * 8;
#pragma unroll
    for (int kt = 0; kt < 8; ++kt){
      short8 wh = *(const short8*)(bh + (size_t)kt * 8 * 512);
      short8 wl = *(const short8*)(bl + (size_t)kt * 8 * 512);
      acc = __builtin_amdgcn_mfma_f32_16x16x32_bf16(ah2[kt], wh, acc, 0, 0, 0);
      acc = __builtin_amdgcn_mfma_f32_16x16x32_bf16(al2[kt], wh, acc, 0, 0, 0);
      acc = __builtin_amdgcn_mfma_f32_16x16x32_bf16(ah2[kt], wl, acc, 0, 0, 0);
    }
    int col = nt * 16 + r16;
#pragma unroll
    for (int r = 0; r < 4; ++r){
      u16 o = f2bf(acc[r]);
      __builtin_nontemporal_store(o, G12 + (size_t)(m0 + quad * 4 + r) * 384 + 256 + col);
    }
  }
}

// ============ merged inc aggregation (dst = A, 50000 rows) =================
// gather weight = s_oi[src] (G1/G2 stored unscaled); epilogues per segment.
__global__ __launch_bounds__(256) void agg_inc2_kernel(
    const u16* __restrict__ G12, const int* __restrict__ off,
    const int* __restrict__ csr, const float* __restrict__ s_oi,
    const float* __restrict__ s_ii, const float* __restrict__ s_ob,
    const float* __restrict__ b1i, const float* __restrict__ b2i,
    u16* __restrict__ Ha, float* __restrict__ outa){
  int wave = blockIdx.x * 4 + (threadIdx.x >> 6);
  int lane = threadIdx.x & 63;
  if (wave >= NA) return;
  int b0 = off[wave], b1 = off[wave + 1];
  int deg = b1 - b0;
  int c1 = lane * 4;
  int c2 = lane * 2;
  float acc[6];
#pragma unroll
  for (int q = 0; q < 6; ++q) acc[q] = 0.f;
  int idx = 0; float sc = 0.f;
  if (lane < deg){
    idx = csr[b0 + lane];
    sc = s_oi[idx];
  }
  int lim = deg < 64 ? deg : 64;
  for (int u = 0; u < lim; u += 4){
    ushort4 va[4]; ushort2 vb[4]; float w[4];
#pragma unroll
    for (int k = 0; k < 4; ++k){
      int e = u + k;
      int t = e < lim ? e : 0;
      int se = __shfl(idx, t, 64);
      float c0 = __shfl(sc, t, 64);
      w[k] = e < lim ? c0 : 0.f;
      const u16* r = G12 + (size_t)se * 384;
      va[k] = *(const ushort4*)(r + c1);
      vb[k] = *(const ushort2*)(r + 256 + c2);
    }
#pragma unroll
    for (int k = 0; k < 4; ++k){
      acc[0] += bf2f(va[k].x) * w[k];
      acc[1] += bf2f(va[k].y) * w[k];
      acc[2] += bf2f(va[k].z) * w[k];
      acc[3] += bf2f(va[k].w) * w[k];
      acc[4] += bf2f(vb[k].x) * w[k];
      acc[5] += bf2f(vb[k].y) * w[k];
    }
  }
  for (int j = b0 + 64; j < b1; ++j){
    int se = csr[j];
    float c0 = s_oi[se];
    const u16* r = G12 + (size_t)se * 384;
    ushort4 va = *(const ushort4*)(r + c1);
    ushort2 vb = *(const ushort2*)(r + 256 + c2);
    acc[0] += bf2f(va.x) * c0; acc[1] += bf2f(va.y) * c0;
    acc[2] += bf2f(va.z) * c0; acc[3] += bf2f(va.w) * c0;
    acc[4] += bf2f(vb.x) * c0; acc[5] += bf2f(vb.y) * c0;
  }
  float sii = s_ii[wave], sob = s_ob[wave];
  float4 bb1 = *(const float4*)(b1i + c1);
  f32x2 bb2 = *(const f32x2*)(b2i + c2);
  u16x4 o1;
  o1.x = f2bf(fmaxf(acc[0] * sii + bb1.x, 0.f) * sob);
  o1.y = f2bf(fmaxf(acc[1] * sii + bb1.y, 0.f) * sob);
  o1.z = f2bf(fmaxf(acc[2] * sii + bb1.z, 0.f) * sob);
  o1.w = f2bf(fmaxf(acc[3] * sii + bb1.w, 0.f) * sob);
  __builtin_nontemporal_store(o1, (u16x4*)(Ha + (size_t)wave * 256 + c1));
  f32x2 o2 = {acc[4] * sii + bb2.x, acc[5] * sii + bb2.y};
  __builtin_nontemporal_store(o2, (f32x2*)(outa + (size_t)wave * 128 + c2));
}

// ================= standalone GEMM (for out_b) =============================
__global__ __launch_bounds__(256) void gemm_kernel(
    const float* __restrict__ A,
    const u16* __restrict__ PWH, const u16* __restrict__ PWL,
    const float* __restrict__ bias, const float* __restrict__ rs,
    float* __restrict__ Cf, u16* __restrict__ C16,
    int M, int nT, int wpsShift, int doRelu, int ldC, int colOff){
  gemm_dev(blockIdx.x, A, PWH, PWL, bias, rs, Cf, C16,
           M, nT, wpsShift, doRelu, ldC, colOff);
}

extern "C" void kernel_launch(void* const* d_in, const int* in_sizes, int n_in,
                              void* d_out, int out_size, void* d_ws, size_t ws_size,
                              hipStream_t stream){
  const float* x_a = (const float*)d_in[0];
  const float* x_b = (const float*)d_in[1];
  const float* W1b = (const float*)d_in[2];
  const float* b1b = (const float*)d_in[3];
  const float* W1i = (const float*)d_in[4];
  const float* b1i = (const float*)d_in[5];
  const float* W2b = (const float*)d_in[6];
  const float* b2b = (const float*)d_in[7];
  const float* W2i = (const float*)d_in[8];
  const float* b2i = (const float*)d_in[9];
  const int* bs  = (const int*)d_in[10];
  const int* bd  = (const int*)d_in[11];
  const int* isc = (const int*)d_in[12];
  const int* idt = (const int*)d_in[13];

  char* w = (char*)d_ws;
  size_t o = 0;
  auto take = [&](size_t bytes) -> void* {
    void* p = w + o; o = (o + bytes + 255) & ~(size_t)255; return p;
  };
  // 4 degree counters, padded: 1 counter per 128B line (CS=32 ints)
  int* zint = (int*)take((size_t)120000 * CS * sizeof(int));
  int* c_bs = zint;
  int* c_bd = zint + (size_t)50000 * CS;
  int* c_is = zint + (size_t)60000 * CS;
  int* c_id = zint + (size_t)70000 * CS;
  int* rank_bel = (int*)take(NE * sizeof(int));
  int* rank_inc = (int*)take(NE * sizeof(int));
  int* off_bel = (int*)take((NB + 1) * sizeof(int));
  int* off_inc = (int*)take((NA + 1) * sizeof(int));
  int* csr_bel = (int*)take(NE * sizeof(int));
  int* csr_inc = (int*)take(NE * sizeof(int));
  float* s_ob = (float*)take(NA * sizeof(float));
  float* s_ib = (float*)take(NB * sizeof(float));
  float* s_oi = (float*)take(NB * sizeof(float));
  float* s_ii = (float*)take(NA * sizeof(float));
  u16* pwh = (u16*)take(196608 * sizeof(u16));
  u16* pwl = (u16*)take(196608 * sizeof(u16));
  u16* pwh1b = pwh, *pwh1i = pwh + 65536, *pwh2b = pwh + 131072, *pwh2i = pwh + 163840;
  u16* pwl1b = pwl, *pwl1i = pwl + 65536, *pwl2b = pwl + 131072, *pwl2i = pwl + 163840;
  u16* xa16 = (u16*)take((size_t)NA * 256 * sizeof(u16));   // x_a bf16 (unscaled)
  u16* G12  = (u16*)take((size_t)NB * 384 * sizeof(u16));   // [G1 256 | G2 128] bf16
  u16* H_a  = (u16*)take((size_t)NA * 256 * sizeof(u16));   // relu(L1 inc)*s_ob, bf16
  float* P_b = (float*)take((size_t)NB * 256 * sizeof(float)); // bel agg out (reused)

  float* out_a = (float*)d_out;                     // [NA,128]
  float* out_b = (float*)d_out + (size_t)NA * 128;  // [NB,128]

  // ---- setup ----
  pre_kernel<<<512, 256, 0, stream>>>(zint, 120000 * CS / 4, W1i, pwh, pwl);
  // [G1 gemm | hist+ranks | pack W1b/W2b/W2i | cvt x_a] in ONE dispatch
  mega_kernel<<<GB + HB + PB + CB, 256, 0, stream>>>(
      x_b, pwh1i, pwl1i, G12,
      bs, bd, isc, idt, c_bs, c_bd, c_is, c_id, rank_bel, rank_inc,
      W1b, W2b, W2i, pwh, pwl, x_a, xa16);
  scan_scales_kernel<<<52, 1024, 0, stream>>>(c_bs, c_bd, c_is, c_id,
                                              off_bel, off_inc,
                                              s_ob, s_ib, s_oi, s_ii);
  fill_kernel<<<1172, 256, 0, stream>>>(bs, bd, isc, idt, rank_bel, rank_inc,
                                        off_bel, off_inc, csr_bel, csr_inc);
  // ---- compute ----
  // P_b = agg_bel(xa16 * s_ob[src])
  agg_bel_kernel<<<2500, 256, 0, stream>>>(xa16, s_ob, off_bel, csr_bel, P_b, NB);
  // H_b (LDS-only) = relu((P_b@W1b)*s_ib+b1b); G2 = H_b@W2i -> G12 cols 256..
  gemmHG_kernel<<<625, 256, 0, stream>>>(P_b, pwh1b, pwl1b, b1b, s_ib,
                                         pwh2i, pwl2i, G12);
  // merged inc agg (weight s_oi[src]): H_a (bf16, pre-scaled s_ob) + out_a
  agg_inc2_kernel<<<12500, 256, 0, stream>>>(G12, off_inc, csr_inc, s_oi,
                                             s_ii, s_ob, b1i, b2i, H_a, out_a);
  // P_b = agg_bel(H_a)  (H_a already src-scaled)
  agg_bel_kernel<<<2500, 256, 0, stream>>>(H_a, nullptr, off_bel, csr_bel, P_b, NB);
  // out_b = (P_b@W2b)*s_ib + b2b
  gemm_kernel<<<625, 256, 0, stream>>>(P_b, pwh2b, pwl2b, b2b, s_ib,
                                       out_b, nullptr, NB, 8, 2, 0, 128, 0);
}

// Round 3
// 401.043 us; speedup vs baseline: 1.2145x; 1.2145x over previous
//
#include <hip/hip_runtime.h>

// RGCN bipartite, FP32 in/out. Round 14 (9 dispatches):
//   - KEEP round-13 padded degree counters (CS=32 ints = 128B/counter).
//     r13 arithmetic says padding sped mega's hist ~20-45us (mega fell out
//     of top-5) but the scan regressed 15->168us and masked it.
//   - FIX scan: per-thread segment cached in REGISTERS (compile-time SEG,
//     unrolled loads -> full MLP; no dependent re-read in the write pass).
//     SEG=10 (NB block) / SEG=49 (NA block).
//   - everything else identical to round 13 (= round 11 structure).

#define NA 50000
#define NB 10000
#define NE 300000
#define GB 625      // mega: gemm blocks
#define HB 1172     // mega: hist blocks
#define PB 64       // mega: pack blocks
#define CB 300      // mega: cvt blocks
#define CS 32       // counter stride (ints) -> 128B per counter

typedef unsigned short u16;
typedef unsigned int u32;
typedef __attribute__((ext_vector_type(8))) short short8;
typedef __attribute__((ext_vector_type(4))) float f32x4;
typedef __attribute__((ext_vector_type(2))) float f32x2;
typedef __attribute__((ext_vector_type(4))) unsigned short u16x4;
typedef __attribute__((ext_vector_type(4))) int i32x4;

__device__ __forceinline__ float bf2f(u16 h){
  union { u32 u; float f; } x; x.u = ((u32)h) << 16; return x.f;
}
__device__ __forceinline__ u16 f2bf(float f){
  union { float f; u32 u; } x; x.f = f;
  u32 r = (x.u + 0x7FFFu + ((x.u >> 16) & 1u)) >> 16;   // RNE
  return (u16)r;
}

// pack element t of the global layout [W1b 64k][W1i 64k][W2b 32k][W2i 32k]
__device__ __forceinline__ void pack_elem(int t,
    const float* __restrict__ W1b, const float* __restrict__ W1i,
    const float* __restrict__ W2b, const float* __restrict__ W2i,
    u16* __restrict__ pwh, u16* __restrict__ pwl){
  const float* W; int N; int tt;
  if (t < 65536)       { W = W1b; N = 256; tt = t; }
  else if (t < 131072) { W = W1i; N = 256; tt = t - 65536; }
  else if (t < 163840) { W = W2b; N = 128; tt = t - 131072; }
  else                 { W = W2i; N = 128; tt = t - 163840; }
  int j = tt & 7, lane = (tt >> 3) & 63, tile = tt >> 9;
  int nT = N >> 4;
  int nt = tile % nT, kt = tile / nT;
  int k = kt * 32 + ((lane >> 4) << 3) + j;
  int n = nt * 16 + (lane & 15);
  float v = W[k * N + n];
  u16 hi = f2bf(v);
  pwh[t] = hi;
  pwl[t] = f2bf(v - bf2f(hi));
}

// ====== pre: zero padded counters (int4) + pack W1i (G1 gemm operand) ======
__global__ __launch_bounds__(256) void pre_kernel(
    int* __restrict__ z, int nz4, const float* __restrict__ W1i,
    u16* __restrict__ pwh, u16* __restrict__ pwl){
  int g = blockIdx.x * blockDim.x + threadIdx.x;
  int s = gridDim.x * blockDim.x;
  i32x4* z4 = (i32x4*)z;
  i32x4 zero = {0, 0, 0, 0};
  for (int i = g; i < nz4; i += s) __builtin_nontemporal_store(zero, z4 + i);
  for (int t = g; t < 65536; t += s)
    pack_elem(65536 + t, nullptr, W1i, nullptr, nullptr, pwh, pwl);
}

// ================= gemm device fn (single live acc, no spills) =============
__device__ __forceinline__ void gemm_dev(int blk, const float* __restrict__ A,
                                         const u16* __restrict__ PWH,
                                         const u16* __restrict__ PWL,
                                         const float* __restrict__ bias,
                                         const float* __restrict__ rs,
                                         float* __restrict__ Cf,
                                         u16* __restrict__ C16,
                                         int M, int nT, int wpsShift,
                                         int doRelu, int ldC, int colOff){
  int wave = blk * 4 + (threadIdx.x >> 6);
  int lane = threadIdx.x & 63;
  int strips = M >> 4;
  int strip = wave >> wpsShift;
  if (strip >= strips) return;
  int slice = wave & ((1 << wpsShift) - 1);
  int ntPer = nT >> wpsShift;
  int ntStart = slice * ntPer;
  int r16 = lane & 15, quad = lane >> 4;
  int m0 = strip << 4;
  const float* aBase = A + (size_t)(m0 + r16) * 256 + quad * 8;
  short8 ah[8], al[8];
#pragma unroll
  for (int kt = 0; kt < 8; ++kt){
    float4 p0 = *(const float4*)(aBase + kt * 32);
    float4 p1 = *(const float4*)(aBase + kt * 32 + 4);
    float v[8] = {p0.x, p0.y, p0.z, p0.w, p1.x, p1.y, p1.z, p1.w};
    short8 h, l;
#pragma unroll
    for (int j = 0; j < 8; ++j){
      u16 hb = f2bf(v[j]);
      h[j] = (short)hb;
      l[j] = (short)f2bf(v[j] - bf2f(hb));
    }
    ah[kt] = h; al[kt] = l;
  }
  float rscale[4];
#pragma unroll
  for (int r = 0; r < 4; ++r) rscale[r] = rs ? rs[m0 + quad * 4 + r] : 1.f;
  for (int nt = ntStart; nt < ntStart + ntPer; ++nt){
    f32x4 acc = {0.f, 0.f, 0.f, 0.f};
    const u16* bh = PWH + ((size_t)nt * 64 + lane) * 8;
    const u16* bl = PWL + ((size_t)nt * 64 + lane) * 8;
#pragma unroll
    for (int kt = 0; kt < 8; ++kt){
      short8 wh = *(const short8*)(bh + (size_t)kt * nT * 512);
      short8 wl = *(const short8*)(bl + (size_t)kt * nT * 512);
      acc = __builtin_amdgcn_mfma_f32_16x16x32_bf16(ah[kt], wh, acc, 0, 0, 0);
      acc = __builtin_amdgcn_mfma_f32_16x16x32_bf16(al[kt], wh, acc, 0, 0, 0);
      acc = __builtin_amdgcn_mfma_f32_16x16x32_bf16(ah[kt], wl, acc, 0, 0, 0);
    }
    int col = nt * 16 + r16;
    float bv = bias ? bias[col] : 0.f;
#pragma unroll
    for (int r = 0; r < 4; ++r){
      float v = acc[r] * rscale[r] + bv;
      if (doRelu) v = fmaxf(v, 0.f);
      size_t o = (size_t)(m0 + quad * 4 + r) * ldC + colOff + col;
      if (C16) __builtin_nontemporal_store(f2bf(v), C16 + o);
      else     __builtin_nontemporal_store(v, Cf + o);
    }
  }
}

// ====== MEGA: [G1 gemm | hist+ranks | pack rest | cvt x_a] block-split =====
__global__ __launch_bounds__(256) void mega_kernel(
    const float* __restrict__ xb,
    const u16* __restrict__ WH1i, const u16* __restrict__ WL1i,
    u16* __restrict__ G12,
    const int* __restrict__ bs, const int* __restrict__ bd,
    const int* __restrict__ isc, const int* __restrict__ idt,
    int* __restrict__ c_bs, int* __restrict__ c_bd,
    int* __restrict__ c_is, int* __restrict__ c_id,
    int* __restrict__ rank_bel, int* __restrict__ rank_inc,
    const float* __restrict__ W1b, const float* __restrict__ W2b,
    const float* __restrict__ W2i,
    u16* __restrict__ pwh, u16* __restrict__ pwl,
    const float* __restrict__ xa, u16* __restrict__ xa16){
  int blk = blockIdx.x;
  if (blk < GB){
    // G1 = x_b @ W1i (UNSCALED; s_oi applied at gather) -> G12 cols [0,256)
    gemm_dev(blk, xb, WH1i, WL1i, nullptr, nullptr,
             nullptr, G12, NB, 16, 2, 0, 384, 0);
  } else if (blk < GB + HB){
    int g = (blk - GB) * blockDim.x + threadIdx.x;
    int s = HB * blockDim.x;
    for (int e = g; e < NE; e += s){
      atomicAdd(&c_bs[bs[e] * CS], 1);
      rank_bel[e] = atomicAdd(&c_bd[bd[e] * CS], 1);
      atomicAdd(&c_is[isc[e] * CS], 1);
      rank_inc[e] = atomicAdd(&c_id[idt[e] * CS], 1);
    }
  } else if (blk < GB + HB + PB){
    int g = (blk - GB - HB) * blockDim.x + threadIdx.x;
    int s = PB * blockDim.x;
    for (int v = g; v < 131072; v += s){
      int t = v < 65536 ? v : v + 65536;   // skip W1i range (packed in pre)
      pack_elem(t, W1b, nullptr, W2b, W2i, pwh, pwl);
    }
  } else {
    int g = ((blk - GB - HB - PB) * blockDim.x + threadIdx.x) * 4;
    int s = CB * blockDim.x * 4;
    for (int i = g; i < NA * 256; i += s){
      float4 v = *(const float4*)(xa + i);
      u16x4 o;
      o.x = f2bf(v.x); o.y = f2bf(v.y); o.z = f2bf(v.z); o.w = f2bf(v.w);
      __builtin_nontemporal_store(o, (u16x4*)(xa16 + i));
    }
  }
}

// ====== scan block: per-thread SEG values cached in registers ==============
template<int SEG>
__device__ __forceinline__ void scan_block(const int* __restrict__ cnt,
                                           int* __restrict__ off, int n){
  __shared__ int wsum[16];
  int tid = threadIdx.x, lane = tid & 63, wid = tid >> 6;
  int i0 = tid * SEG;
  int v[SEG];
#pragma unroll
  for (int r = 0; r < SEG; ++r){
    int idx = i0 + r;
    v[r] = (idx < n) ? cnt[idx * CS] : 0;
  }
  int sum = 0;
#pragma unroll
  for (int r = 0; r < SEG; ++r) sum += v[r];
  int x = sum;
#pragma unroll
  for (int d = 1; d < 64; d <<= 1){
    int t = __shfl_up(x, d, 64);
    if (lane >= d) x += t;
  }
  if (lane == 63) wsum[wid] = x;
  __syncthreads();
  if (wid == 0){
    int ws = (lane < 16) ? wsum[lane] : 0;
#pragma unroll
    for (int d = 1; d < 16; d <<= 1){
      int t = __shfl_up(ws, d, 64);
      if (lane >= d) ws += t;
    }
    if (lane < 16) wsum[lane] = ws;
  }
  __syncthreads();
  int run = (wid ? wsum[wid - 1] : 0) + (x - sum);
#pragma unroll
  for (int r = 0; r < SEG; ++r){
    int idx = i0 + r;
    if (idx < n) off[idx] = run;
    run += v[r];
  }
  if (tid == 0) off[n] = wsum[15];
}

// ============ scan (blocks 0,1) + scales (blocks 2..) ======================
__global__ __launch_bounds__(1024) void scan_scales_kernel(
    const int* __restrict__ c_bs, const int* __restrict__ c_bd,
    const int* __restrict__ c_is, const int* __restrict__ c_id,
    int* __restrict__ off_bel, int* __restrict__ off_inc,
    float* __restrict__ s_ob, float* __restrict__ s_ib,
    float* __restrict__ s_oi, float* __restrict__ s_ii){
  if (blockIdx.x >= 2){
    int g = (blockIdx.x - 2) * blockDim.x + threadIdx.x;
    int s = (gridDim.x - 2) * blockDim.x;
    for (int i = g; i < NA; i += s){
      int a = c_bs[i * CS]; s_ob[i] = rsqrtf((float)(a > 1 ? a : 1));
      int b = c_id[i * CS]; s_ii[i] = rsqrtf((float)(b > 1 ? b : 1));
      if (i < NB){
        int c = c_bd[i * CS]; s_ib[i] = rsqrtf((float)(c > 1 ? c : 1));
        int d = c_is[i * CS]; s_oi[i] = rsqrtf((float)(d > 1 ? d : 1));
      }
    }
    return;
  }
  if (blockIdx.x == 0) scan_block<10>(c_bd, off_bel, NB);
  else                 scan_block<49>(c_id, off_inc, NA);
}

// ============ CSR fill: NO atomics (slot = off[dst] + rank[e]) =============
__global__ __launch_bounds__(256) void fill_kernel(
    const int* __restrict__ bs, const int* __restrict__ bd,
    const int* __restrict__ isc, const int* __restrict__ idt,
    const int* __restrict__ rank_bel, const int* __restrict__ rank_inc,
    const int* __restrict__ off_bel, const int* __restrict__ off_inc,
    int* __restrict__ csr_bel, int* __restrict__ csr_inc){
  int g = blockIdx.x * blockDim.x + threadIdx.x;
  int s = gridDim.x * blockDim.x;
  for (int e = g; e < NE; e += s){
    csr_bel[off_bel[bd[e]] + rank_bel[e]] = bs[e];
    csr_inc[off_inc[idt[e]] + rank_inc[e]] = isc[e];
  }
}

// ================= bel aggregation (dst = B, 10000 rows) ===================
__global__ __launch_bounds__(256) void agg_bel_kernel(
    const u16* __restrict__ X, const float* __restrict__ ss,
    const int* __restrict__ off, const int* __restrict__ csr,
    float* __restrict__ Pf, int nDst){
  int wave = blockIdx.x * 4 + (threadIdx.x >> 6);
  int lane = threadIdx.x & 63;
  if (wave >= nDst) return;
  int b0 = off[wave], b1 = off[wave + 1];
  int deg = b1 - b0;
  int part = lane >> 5;
  int cl = lane & 31;
  int c = cl * 8;
  float acc[8];
#pragma unroll
  for (int q = 0; q < 8; ++q) acc[q] = 0.f;
  int idx = 0; float sc = 0.f;
  if (lane < deg){
    idx = csr[b0 + lane];
    sc = ss ? ss[idx] : 1.f;
  }
  int lim = deg < 64 ? deg : 64;
  for (int u = 0; u < lim; u += 8){
    const u16* addr[4]; float w[4];
#pragma unroll
    for (int k = 0; k < 4; ++k){
      int e = u + k * 2 + part;
      int t = e < lim ? e : 0;
      int s0 = __shfl(idx, t, 64);
      float c0 = __shfl(sc, t, 64);
      w[k] = e < lim ? c0 : 0.f;
      addr[k] = X + (size_t)s0 * 256 + c;
    }
    short8 v[4];
#pragma unroll
    for (int k = 0; k < 4; ++k) v[k] = *(const short8*)addr[k];
#pragma unroll
    for (int k = 0; k < 4; ++k)
#pragma unroll
      for (int q = 0; q < 8; ++q) acc[q] += bf2f((u16)v[k][q]) * w[k];
  }
  for (int j = b0 + 64 + part; j < b1; j += 2){
    int s0 = csr[j];
    float c0 = ss ? ss[s0] : 1.f;
    short8 v0 = *(const short8*)(X + (size_t)s0 * 256 + c);
#pragma unroll
    for (int q = 0; q < 8; ++q) acc[q] += bf2f((u16)v0[q]) * c0;
  }
#pragma unroll
  for (int q = 0; q < 8; ++q) acc[q] += __shfl_xor(acc[q], 32, 64);
  if (part == 0){
    f32x4 f0 = {acc[0], acc[1], acc[2], acc[3]};
    f32x4 f1 = {acc[4], acc[5], acc[6], acc[7]};
    __builtin_nontemporal_store(f0, (f32x4*)(Pf + (size_t)wave * 256 + c));
    __builtin_nontemporal_store(f1, (f32x4*)(Pf + (size_t)wave * 256 + c + 4));
  }
}

// ====== gemmHG: H_b strip -> LDS fp32 -> G2 gemm (UNSCALED), per strip =====
__global__ __launch_bounds__(256) void gemmHG_kernel(
    const float* __restrict__ Pb,
    const u16* __restrict__ WH1b, const u16* __restrict__ WL1b,
    const float* __restrict__ b1b, const float* __restrict__ s_ib,
    const u16* __restrict__ WH2i, const u16* __restrict__ WL2i,
    u16* __restrict__ G12){
  __shared__ float Hs[16][260];
  int w = threadIdx.x >> 6;
  int lane = threadIdx.x & 63;
  int r16 = lane & 15, quad = lane >> 4;
  int m0 = blockIdx.x << 4;
  // ---- phase 1: H_b = relu((P_b@W1b)*s_ib + b1b) into LDS ----
  const float* aBase = Pb + (size_t)(m0 + r16) * 256 + quad * 8;
  short8 ah[8], al[8];
#pragma unroll
  for (int kt = 0; kt < 8; ++kt){
    float4 p0 = *(const float4*)(aBase + kt * 32);
    float4 p1 = *(const float4*)(aBase + kt * 32 + 4);
    float v[8] = {p0.x, p0.y, p0.z, p0.w, p1.x, p1.y, p1.z, p1.w};
    short8 h, l;
#pragma unroll
    for (int j = 0; j < 8; ++j){
      u16 hb = f2bf(v[j]);
      h[j] = (short)hb;
      l[j] = (short)f2bf(v[j] - bf2f(hb));
    }
    ah[kt] = h; al[kt] = l;
  }
  float rs1[4];
#pragma unroll
  for (int r = 0; r < 4; ++r) rs1[r] = s_ib[m0 + quad * 4 + r];
  for (int nt = w * 4; nt < w * 4 + 4; ++nt){
    f32x4 acc = {0.f, 0.f, 0.f, 0.f};
    const u16* bh = WH1b + ((size_t)nt * 64 + lane) * 8;
    const u16* bl = WL1b + ((size_t)nt * 64 + lane) * 8;
#pragma unroll
    for (int kt = 0; kt < 8; ++kt){
      short8 wh = *(const short8*)(bh + (size_t)kt * 16 * 512);
      short8 wl = *(const short8*)(bl + (size_t)kt * 16 * 512);
      acc = __builtin_amdgcn_mfma_f32_16x16x32_bf16(ah[kt], wh, acc, 0, 0, 0);
      acc = __builtin_amdgcn_mfma_f32_16x16x32_bf16(al[kt], wh, acc, 0, 0, 0);
      acc = __builtin_amdgcn_mfma_f32_16x16x32_bf16(ah[kt], wl, acc, 0, 0, 0);
    }
    int col = nt * 16 + r16;
    float bv = b1b[col];
#pragma unroll
    for (int r = 0; r < 4; ++r)
      Hs[quad * 4 + r][col] = fmaxf(acc[r] * rs1[r] + bv, 0.f);
  }
  __syncthreads();
  // ---- phase 2: G2 = H_b @ W2i (UNSCALED) -> G12 cols [256,384) ----
  short8 ah2[8], al2[8];
#pragma unroll
  for (int kt = 0; kt < 8; ++kt){
    float4 p0 = *(const float4*)&Hs[r16][kt * 32 + quad * 8];
    float4 p1 = *(const float4*)&Hs[r16][kt * 32 + quad * 8 + 4];
    float v[8] = {p0.x, p0.y, p0.z, p0.w, p1.x, p1.y, p1.z, p1.w};
    short8 h, l;
#pragma unroll
    for (int j = 0; j < 8; ++j){
      u16 hb = f2bf(v[j]);
      h[j] = (short)hb;
      l[j] = (short)f2bf(v[j] - bf2f(hb));
    }
    ah2[kt] = h; al2[kt] = l;
  }
  for (int nt = w * 2; nt < w * 2 + 2; ++nt){
    f32x4 acc = {0.f, 0.f, 0.f, 0.f};
    const u16* bh = WH2i + ((size_t)nt * 64 + lane) * 8;
    const u16* bl = WL2i + ((size_t)nt * 64 + lane) * 8;
#pragma unroll
    for (int kt = 0; kt < 8; ++kt){
      short8 wh = *(const short8*)(bh + (size_t)kt * 8 * 512);
      short8 wl = *(const short8*)(bl + (size_t)kt * 8 * 512);
      acc = __builtin_amdgcn_mfma_f32_16x16x32_bf16(ah2[kt], wh, acc, 0, 0, 0);
      acc = __builtin_amdgcn_mfma_f32_16x16x32_bf16(al2[kt], wh, acc, 0, 0, 0);
      acc = __builtin_amdgcn_mfma_f32_16x16x32_bf16(ah2[kt], wl, acc, 0, 0, 0);
    }
    int col = nt * 16 + r16;
#pragma unroll
    for (int r = 0; r < 4; ++r){
      u16 o = f2bf(acc[r]);
      __builtin_nontemporal_store(o, G12 + (size_t)(m0 + quad * 4 + r) * 384 + 256 + col);
    }
  }
}

// ============ merged inc aggregation (dst = A, 50000 rows) =================
// gather weight = s_oi[src] (G1/G2 stored unscaled); epilogues per segment.
__global__ __launch_bounds__(256) void agg_inc2_kernel(
    const u16* __restrict__ G12, const int* __restrict__ off,
    const int* __restrict__ csr, const float* __restrict__ s_oi,
    const float* __restrict__ s_ii, const float* __restrict__ s_ob,
    const float* __restrict__ b1i, const float* __restrict__ b2i,
    u16* __restrict__ Ha, float* __restrict__ outa){
  int wave = blockIdx.x * 4 + (threadIdx.x >> 6);
  int lane = threadIdx.x & 63;
  if (wave >= NA) return;
  int b0 = off[wave], b1 = off[wave + 1];
  int deg = b1 - b0;
  int c1 = lane * 4;
  int c2 = lane * 2;
  float acc[6];
#pragma unroll
  for (int q = 0; q < 6; ++q) acc[q] = 0.f;
  int idx = 0; float sc = 0.f;
  if (lane < deg){
    idx = csr[b0 + lane];
    sc = s_oi[idx];
  }
  int lim = deg < 64 ? deg : 64;
  for (int u = 0; u < lim; u += 4){
    ushort4 va[4]; ushort2 vb[4]; float w[4];
#pragma unroll
    for (int k = 0; k < 4; ++k){
      int e = u + k;
      int t = e < lim ? e : 0;
      int se = __shfl(idx, t, 64);
      float c0 = __shfl(sc, t, 64);
      w[k] = e < lim ? c0 : 0.f;
      const u16* r = G12 + (size_t)se * 384;
      va[k] = *(const ushort4*)(r + c1);
      vb[k] = *(const ushort2*)(r + 256 + c2);
    }
#pragma unroll
    for (int k = 0; k < 4; ++k){
      acc[0] += bf2f(va[k].x) * w[k];
      acc[1] += bf2f(va[k].y) * w[k];
      acc[2] += bf2f(va[k].z) * w[k];
      acc[3] += bf2f(va[k].w) * w[k];
      acc[4] += bf2f(vb[k].x) * w[k];
      acc[5] += bf2f(vb[k].y) * w[k];
    }
  }
  for (int j = b0 + 64; j < b1; ++j){
    int se = csr[j];
    float c0 = s_oi[se];
    const u16* r = G12 + (size_t)se * 384;
    ushort4 va = *(const ushort4*)(r + c1);
    ushort2 vb = *(const ushort2*)(r + 256 + c2);
    acc[0] += bf2f(va.x) * c0; acc[1] += bf2f(va.y) * c0;
    acc[2] += bf2f(va.z) * c0; acc[3] += bf2f(va.w) * c0;
    acc[4] += bf2f(vb.x) * c0; acc[5] += bf2f(vb.y) * c0;
  }
  float sii = s_ii[wave], sob = s_ob[wave];
  float4 bb1 = *(const float4*)(b1i + c1);
  f32x2 bb2 = *(const f32x2*)(b2i + c2);
  u16x4 o1;
  o1.x = f2bf(fmaxf(acc[0] * sii + bb1.x, 0.f) * sob);
  o1.y = f2bf(fmaxf(acc[1] * sii + bb1.y, 0.f) * sob);
  o1.z = f2bf(fmaxf(acc[2] * sii + bb1.z, 0.f) * sob);
  o1.w = f2bf(fmaxf(acc[3] * sii + bb1.w, 0.f) * sob);
  __builtin_nontemporal_store(o1, (u16x4*)(Ha + (size_t)wave * 256 + c1));
  f32x2 o2 = {acc[4] * sii + bb2.x, acc[5] * sii + bb2.y};
  __builtin_nontemporal_store(o2, (f32x2*)(outa + (size_t)wave * 128 + c2));
}

// ================= standalone GEMM (for out_b) =============================
__global__ __launch_bounds__(256) void gemm_kernel(
    const float* __restrict__ A,
    const u16* __restrict__ PWH, const u16* __restrict__ PWL,
    const float* __restrict__ bias, const float* __restrict__ rs,
    float* __restrict__ Cf, u16* __restrict__ C16,
    int M, int nT, int wpsShift, int doRelu, int ldC, int colOff){
  gemm_dev(blockIdx.x, A, PWH, PWL, bias, rs, Cf, C16,
           M, nT, wpsShift, doRelu, ldC, colOff);
}

extern "C" void kernel_launch(void* const* d_in, const int* in_sizes, int n_in,
                              void* d_out, int out_size, void* d_ws, size_t ws_size,
                              hipStream_t stream){
  const float* x_a = (const float*)d_in[0];
  const float* x_b = (const float*)d_in[1];
  const float* W1b = (const float*)d_in[2];
  const float* b1b = (const float*)d_in[3];
  const float* W1i = (const float*)d_in[4];
  const float* b1i = (const float*)d_in[5];
  const float* W2b = (const float*)d_in[6];
  const float* b2b = (const float*)d_in[7];
  const float* W2i = (const float*)d_in[8];
  const float* b2i = (const float*)d_in[9];
  const int* bs  = (const int*)d_in[10];
  const int* bd  = (const int*)d_in[11];
  const int* isc = (const int*)d_in[12];
  const int* idt = (const int*)d_in[13];

  char* w = (char*)d_ws;
  size_t o = 0;
  auto take = [&](size_t bytes) -> void* {
    void* p = w + o; o = (o + bytes + 255) & ~(size_t)255; return p;
  };
  // 4 degree counters, padded: 1 counter per 128B line (CS=32 ints)
  int* zint = (int*)take((size_t)120000 * CS * sizeof(int));
  int* c_bs = zint;
  int* c_bd = zint + (size_t)50000 * CS;
  int* c_is = zint + (size_t)60000 * CS;
  int* c_id = zint + (size_t)70000 * CS;
  int* rank_bel = (int*)take(NE * sizeof(int));
  int* rank_inc = (int*)take(NE * sizeof(int));
  int* off_bel = (int*)take((NB + 1) * sizeof(int));
  int* off_inc = (int*)take((NA + 1) * sizeof(int));
  int* csr_bel = (int*)take(NE * sizeof(int));
  int* csr_inc = (int*)take(NE * sizeof(int));
  float* s_ob = (float*)take(NA * sizeof(float));
  float* s_ib = (float*)take(NB * sizeof(float));
  float* s_oi = (float*)take(NB * sizeof(float));
  float* s_ii = (float*)take(NA * sizeof(float));
  u16* pwh = (u16*)take(196608 * sizeof(u16));
  u16* pwl = (u16*)take(196608 * sizeof(u16));
  u16* pwh1b = pwh, *pwh1i = pwh + 65536, *pwh2b = pwh + 131072, *pwh2i = pwh + 163840;
  u16* pwl1b = pwl, *pwl1i = pwl + 65536, *pwl2b = pwl + 131072, *pwl2i = pwl + 163840;
  u16* xa16 = (u16*)take((size_t)NA * 256 * sizeof(u16));   // x_a bf16 (unscaled)
  u16* G12  = (u16*)take((size_t)NB * 384 * sizeof(u16));   // [G1 256 | G2 128] bf16
  u16* H_a  = (u16*)take((size_t)NA * 256 * sizeof(u16));   // relu(L1 inc)*s_ob, bf16
  float* P_b = (float*)take((size_t)NB * 256 * sizeof(float)); // bel agg out (reused)

  float* out_a = (float*)d_out;                     // [NA,128]
  float* out_b = (float*)d_out + (size_t)NA * 128;  // [NB,128]

  // ---- setup ----
  pre_kernel<<<512, 256, 0, stream>>>(zint, 120000 * CS / 4, W1i, pwh, pwl);
  // [G1 gemm | hist+ranks | pack W1b/W2b/W2i | cvt x_a] in ONE dispatch
  mega_kernel<<<GB + HB + PB + CB, 256, 0, stream>>>(
      x_b, pwh1i, pwl1i, G12,
      bs, bd, isc, idt, c_bs, c_bd, c_is, c_id, rank_bel, rank_inc,
      W1b, W2b, W2i, pwh, pwl, x_a, xa16);
  scan_scales_kernel<<<52, 1024, 0, stream>>>(c_bs, c_bd, c_is, c_id,
                                              off_bel, off_inc,
                                              s_ob, s_ib, s_oi, s_ii);
  fill_kernel<<<1172, 256, 0, stream>>>(bs, bd, isc, idt, rank_bel, rank_inc,
                                        off_bel, off_inc, csr_bel, csr_inc);
  // ---- compute ----
  // P_b = agg_bel(xa16 * s_ob[src])
  agg_bel_kernel<<<2500, 256, 0, stream>>>(xa16, s_ob, off_bel, csr_bel, P_b, NB);
  // H_b (LDS-only) = relu((P_b@W1b)*s_ib+b1b); G2 = H_b@W2i -> G12 cols 256..
  gemmHG_kernel<<<625, 256, 0, stream>>>(P_b, pwh1b, pwl1b, b1b, s_ib,
                                         pwh2i, pwl2i, G12);
  // merged inc agg (weight s_oi[src]): H_a (bf16, pre-scaled s_ob) + out_a
  agg_inc2_kernel<<<12500, 256, 0, stream>>>(G12, off_inc, csr_inc, s_oi,
                                             s_ii, s_ob, b1i, b2i, H_a, out_a);
  // P_b = agg_bel(H_a)  (H_a already src-scaled)
  agg_bel_kernel<<<2500, 256, 0, stream>>>(H_a, nullptr, off_bel, csr_bel, P_b, NB);
  // out_b = (P_b@W2b)*s_ib + b2b
  gemm_kernel<<<625, 256, 0, stream>>>(P_b, pwh2b, pwl2b, b2b, s_ib,
                                       out_b, nullptr, NB, 8, 2, 0, 128, 0);
}

// Round 4
// 363.542 us; speedup vs baseline: 1.3398x; 1.1032x over previous
//
#include <hip/hip_runtime.h>

// RGCN bipartite, FP32 in/out. Round 15 (9 dispatches):
//   - REVERT r13/r14 counter padding (proven NULL for mega: 87us with and
//     without; and padding cost +52us in pre/scan/scales strided access).
//   - NEW: 4-way REPLICATED hot counters. c_bd/c_is average 30 atomics per
//     address (B side); theory = same-ADDRESS serialization at the memory-
//     side atomic unit bounds hist (~60us). Replica r=e&3 cuts chain depth
//     30->7.5. Ranks become rank-within-(dst,replica); CSR slot =
//     off_bel4[bd*4+r]+rank; scan runs over the 40000-entry replicated
//     array so replica segments are contiguous per dst; agg_bel reads
//     off4[4w]..off4[4w+4]. Within-dst order permutes -- already atomic-
//     race nondeterministic. A-side counters (6-deep) stay 1-way.
//   - register scan (r14) kept, now on contiguous data.

#define NA 50000
#define NB 10000
#define NE 300000
#define GB 625      // mega: gemm blocks
#define HB 1172     // mega: hist blocks
#define PB 64       // mega: pack blocks
#define CB 300      // mega: cvt blocks

typedef unsigned short u16;
typedef unsigned int u32;
typedef __attribute__((ext_vector_type(8))) short short8;
typedef __attribute__((ext_vector_type(4))) float f32x4;
typedef __attribute__((ext_vector_type(2))) float f32x2;
typedef __attribute__((ext_vector_type(4))) unsigned short u16x4;
typedef __attribute__((ext_vector_type(4))) int i32x4;

__device__ __forceinline__ float bf2f(u16 h){
  union { u32 u; float f; } x; x.u = ((u32)h) << 16; return x.f;
}
__device__ __forceinline__ u16 f2bf(float f){
  union { float f; u32 u; } x; x.f = f;
  u32 r = (x.u + 0x7FFFu + ((x.u >> 16) & 1u)) >> 16;   // RNE
  return (u16)r;
}

// pack element t of the global layout [W1b 64k][W1i 64k][W2b 32k][W2i 32k]
__device__ __forceinline__ void pack_elem(int t,
    const float* __restrict__ W1b, const float* __restrict__ W1i,
    const float* __restrict__ W2b, const float* __restrict__ W2i,
    u16* __restrict__ pwh, u16* __restrict__ pwl){
  const float* W; int N; int tt;
  if (t < 65536)       { W = W1b; N = 256; tt = t; }
  else if (t < 131072) { W = W1i; N = 256; tt = t - 65536; }
  else if (t < 163840) { W = W2b; N = 128; tt = t - 131072; }
  else                 { W = W2i; N = 128; tt = t - 163840; }
  int j = tt & 7, lane = (tt >> 3) & 63, tile = tt >> 9;
  int nT = N >> 4;
  int nt = tile % nT, kt = tile / nT;
  int k = kt * 32 + ((lane >> 4) << 3) + j;
  int n = nt * 16 + (lane & 15);
  float v = W[k * N + n];
  u16 hi = f2bf(v);
  pwh[t] = hi;
  pwl[t] = f2bf(v - bf2f(hi));
}

// ====== pre: zero counters (int4) + pack W1i (G1 gemm operand) =============
__global__ __launch_bounds__(256) void pre_kernel(
    int* __restrict__ z, int nz4, const float* __restrict__ W1i,
    u16* __restrict__ pwh, u16* __restrict__ pwl){
  int g = blockIdx.x * blockDim.x + threadIdx.x;
  int s = gridDim.x * blockDim.x;
  i32x4* z4 = (i32x4*)z;
  i32x4 zero = {0, 0, 0, 0};
  for (int i = g; i < nz4; i += s) __builtin_nontemporal_store(zero, z4 + i);
  for (int t = g; t < 65536; t += s)
    pack_elem(65536 + t, nullptr, W1i, nullptr, nullptr, pwh, pwl);
}

// ================= gemm device fn (single live acc, no spills) =============
__device__ __forceinline__ void gemm_dev(int blk, const float* __restrict__ A,
                                         const u16* __restrict__ PWH,
                                         const u16* __restrict__ PWL,
                                         const float* __restrict__ bias,
                                         const float* __restrict__ rs,
                                         float* __restrict__ Cf,
                                         u16* __restrict__ C16,
                                         int M, int nT, int wpsShift,
                                         int doRelu, int ldC, int colOff){
  int wave = blk * 4 + (threadIdx.x >> 6);
  int lane = threadIdx.x & 63;
  int strips = M >> 4;
  int strip = wave >> wpsShift;
  if (strip >= strips) return;
  int slice = wave & ((1 << wpsShift) - 1);
  int ntPer = nT >> wpsShift;
  int ntStart = slice * ntPer;
  int r16 = lane & 15, quad = lane >> 4;
  int m0 = strip << 4;
  const float* aBase = A + (size_t)(m0 + r16) * 256 + quad * 8;
  short8 ah[8], al[8];
#pragma unroll
  for (int kt = 0; kt < 8; ++kt){
    float4 p0 = *(const float4*)(aBase + kt * 32);
    float4 p1 = *(const float4*)(aBase + kt * 32 + 4);
    float v[8] = {p0.x, p0.y, p0.z, p0.w, p1.x, p1.y, p1.z, p1.w};
    short8 h, l;
#pragma unroll
    for (int j = 0; j < 8; ++j){
      u16 hb = f2bf(v[j]);
      h[j] = (short)hb;
      l[j] = (short)f2bf(v[j] - bf2f(hb));
    }
    ah[kt] = h; al[kt] = l;
  }
  float rscale[4];
#pragma unroll
  for (int r = 0; r < 4; ++r) rscale[r] = rs ? rs[m0 + quad * 4 + r] : 1.f;
  for (int nt = ntStart; nt < ntStart + ntPer; ++nt){
    f32x4 acc = {0.f, 0.f, 0.f, 0.f};
    const u16* bh = PWH + ((size_t)nt * 64 + lane) * 8;
    const u16* bl = PWL + ((size_t)nt * 64 + lane) * 8;
#pragma unroll
    for (int kt = 0; kt < 8; ++kt){
      short8 wh = *(const short8*)(bh + (size_t)kt * nT * 512);
      short8 wl = *(const short8*)(bl + (size_t)kt * nT * 512);
      acc = __builtin_amdgcn_mfma_f32_16x16x32_bf16(ah[kt], wh, acc, 0, 0, 0);
      acc = __builtin_amdgcn_mfma_f32_16x16x32_bf16(al[kt], wh, acc, 0, 0, 0);
      acc = __builtin_amdgcn_mfma_f32_16x16x32_bf16(ah[kt], wl, acc, 0, 0, 0);
    }
    int col = nt * 16 + r16;
    float bv = bias ? bias[col] : 0.f;
#pragma unroll
    for (int r = 0; r < 4; ++r){
      float v = acc[r] * rscale[r] + bv;
      if (doRelu) v = fmaxf(v, 0.f);
      size_t o = (size_t)(m0 + quad * 4 + r) * ldC + colOff + col;
      if (C16) __builtin_nontemporal_store(f2bf(v), C16 + o);
      else     __builtin_nontemporal_store(v, Cf + o);
    }
  }
}

// ====== MEGA: [G1 gemm | hist+ranks | pack rest | cvt x_a] block-split =====
__global__ __launch_bounds__(256) void mega_kernel(
    const float* __restrict__ xb,
    const u16* __restrict__ WH1i, const u16* __restrict__ WL1i,
    u16* __restrict__ G12,
    const int* __restrict__ bs, const int* __restrict__ bd,
    const int* __restrict__ isc, const int* __restrict__ idt,
    int* __restrict__ c_bs, int* __restrict__ c_bd4,
    int* __restrict__ c_is4, int* __restrict__ c_id,
    int* __restrict__ rank_bel, int* __restrict__ rank_inc,
    const float* __restrict__ W1b, const float* __restrict__ W2b,
    const float* __restrict__ W2i,
    u16* __restrict__ pwh, u16* __restrict__ pwl,
    const float* __restrict__ xa, u16* __restrict__ xa16){
  int blk = blockIdx.x;
  if (blk < GB){
    // G1 = x_b @ W1i (UNSCALED; s_oi applied at gather) -> G12 cols [0,256)
    gemm_dev(blk, xb, WH1i, WL1i, nullptr, nullptr,
             nullptr, G12, NB, 16, 2, 0, 384, 0);
  } else if (blk < GB + HB){
    int g = (blk - GB) * blockDim.x + threadIdx.x;
    int s = HB * blockDim.x;
    for (int e = g; e < NE; e += s){
      int r = e & 3;
      atomicAdd(&c_bs[bs[e]], 1);
      rank_bel[e] = atomicAdd(&c_bd4[bd[e] * 4 + r], 1);
      atomicAdd(&c_is4[isc[e] * 4 + r], 1);
      rank_inc[e] = atomicAdd(&c_id[idt[e]], 1);
    }
  } else if (blk < GB + HB + PB){
    int g = (blk - GB - HB) * blockDim.x + threadIdx.x;
    int s = PB * blockDim.x;
    for (int v = g; v < 131072; v += s){
      int t = v < 65536 ? v : v + 65536;   // skip W1i range (packed in pre)
      pack_elem(t, W1b, nullptr, W2b, W2i, pwh, pwl);
    }
  } else {
    int g = ((blk - GB - HB - PB) * blockDim.x + threadIdx.x) * 4;
    int s = CB * blockDim.x * 4;
    for (int i = g; i < NA * 256; i += s){
      float4 v = *(const float4*)(xa + i);
      u16x4 o;
      o.x = f2bf(v.x); o.y = f2bf(v.y); o.z = f2bf(v.z); o.w = f2bf(v.w);
      __builtin_nontemporal_store(o, (u16x4*)(xa16 + i));
    }
  }
}

// ====== scan block: per-thread SEG values cached in registers ==============
template<int SEG>
__device__ __forceinline__ void scan_block(const int* __restrict__ cnt,
                                           int* __restrict__ off, int n){
  __shared__ int wsum[16];
  int tid = threadIdx.x, lane = tid & 63, wid = tid >> 6;
  int i0 = tid * SEG;
  int v[SEG];
#pragma unroll
  for (int r = 0; r < SEG; ++r){
    int idx = i0 + r;
    v[r] = (idx < n) ? cnt[idx] : 0;
  }
  int sum = 0;
#pragma unroll
  for (int r = 0; r < SEG; ++r) sum += v[r];
  int x = sum;
#pragma unroll
  for (int d = 1; d < 64; d <<= 1){
    int t = __shfl_up(x, d, 64);
    if (lane >= d) x += t;
  }
  if (lane == 63) wsum[wid] = x;
  __syncthreads();
  if (wid == 0){
    int ws = (lane < 16) ? wsum[lane] : 0;
#pragma unroll
    for (int d = 1; d < 16; d <<= 1){
      int t = __shfl_up(ws, d, 64);
      if (lane >= d) ws += t;
    }
    if (lane < 16) wsum[lane] = ws;
  }
  __syncthreads();
  int run = (wid ? wsum[wid - 1] : 0) + (x - sum);
#pragma unroll
  for (int r = 0; r < SEG; ++r){
    int idx = i0 + r;
    if (idx < n) off[idx] = run;
    run += v[r];
  }
  if (tid == 0) off[n] = wsum[15];
}

// ============ scan (blocks 0,1) + scales (blocks 2..) ======================
__global__ __launch_bounds__(1024) void scan_scales_kernel(
    const int* __restrict__ c_bs, const int* __restrict__ c_bd4,
    const int* __restrict__ c_is4, const int* __restrict__ c_id,
    int* __restrict__ off_bel4, int* __restrict__ off_inc,
    float* __restrict__ s_ob, float* __restrict__ s_ib,
    float* __restrict__ s_oi, float* __restrict__ s_ii){
  if (blockIdx.x >= 2){
    int g = (blockIdx.x - 2) * blockDim.x + threadIdx.x;
    int s = (gridDim.x - 2) * blockDim.x;
    for (int i = g; i < NA; i += s){
      int a = c_bs[i]; s_ob[i] = rsqrtf((float)(a > 1 ? a : 1));
      int b = c_id[i]; s_ii[i] = rsqrtf((float)(b > 1 ? b : 1));
      if (i < NB){
        i32x4 cb = *(const i32x4*)(c_bd4 + i * 4);
        int c = cb[0] + cb[1] + cb[2] + cb[3];
        s_ib[i] = rsqrtf((float)(c > 1 ? c : 1));
        i32x4 ci = *(const i32x4*)(c_is4 + i * 4);
        int d = ci[0] + ci[1] + ci[2] + ci[3];
        s_oi[i] = rsqrtf((float)(d > 1 ? d : 1));
      }
    }
    return;
  }
  if (blockIdx.x == 0) scan_block<40>(c_bd4, off_bel4, 40000);
  else                 scan_block<49>(c_id, off_inc, NA);
}

// ============ CSR fill: NO atomics (slot = off[dst*4+rep] + rank[e]) =======
__global__ __launch_bounds__(256) void fill_kernel(
    const int* __restrict__ bs, const int* __restrict__ bd,
    const int* __restrict__ isc, const int* __restrict__ idt,
    const int* __restrict__ rank_bel, const int* __restrict__ rank_inc,
    const int* __restrict__ off_bel4, const int* __restrict__ off_inc,
    int* __restrict__ csr_bel, int* __restrict__ csr_inc){
  int g = blockIdx.x * blockDim.x + threadIdx.x;
  int s = gridDim.x * blockDim.x;
  for (int e = g; e < NE; e += s){
    int r = e & 3;
    csr_bel[off_bel4[bd[e] * 4 + r] + rank_bel[e]] = bs[e];
    csr_inc[off_inc[idt[e]] + rank_inc[e]] = isc[e];
  }
}

// ================= bel aggregation (dst = B, 10000 rows) ===================
// off4 is the 4-way replicated offset array: row w spans off4[4w]..off4[4w+4]
__global__ __launch_bounds__(256) void agg_bel_kernel(
    const u16* __restrict__ X, const float* __restrict__ ss,
    const int* __restrict__ off4, const int* __restrict__ csr,
    float* __restrict__ Pf, int nDst){
  int wave = blockIdx.x * 4 + (threadIdx.x >> 6);
  int lane = threadIdx.x & 63;
  if (wave >= nDst) return;
  int b0 = off4[wave * 4], b1 = off4[wave * 4 + 4];
  int deg = b1 - b0;
  int part = lane >> 5;
  int cl = lane & 31;
  int c = cl * 8;
  float acc[8];
#pragma unroll
  for (int q = 0; q < 8; ++q) acc[q] = 0.f;
  int idx = 0; float sc = 0.f;
  if (lane < deg){
    idx = csr[b0 + lane];
    sc = ss ? ss[idx] : 1.f;
  }
  int lim = deg < 64 ? deg : 64;
  for (int u = 0; u < lim; u += 8){
    const u16* addr[4]; float w[4];
#pragma unroll
    for (int k = 0; k < 4; ++k){
      int e = u + k * 2 + part;
      int t = e < lim ? e : 0;
      int s0 = __shfl(idx, t, 64);
      float c0 = __shfl(sc, t, 64);
      w[k] = e < lim ? c0 : 0.f;
      addr[k] = X + (size_t)s0 * 256 + c;
    }
    short8 v[4];
#pragma unroll
    for (int k = 0; k < 4; ++k) v[k] = *(const short8*)addr[k];
#pragma unroll
    for (int k = 0; k < 4; ++k)
#pragma unroll
      for (int q = 0; q < 8; ++q) acc[q] += bf2f((u16)v[k][q]) * w[k];
  }
  for (int j = b0 + 64 + part; j < b1; j += 2){
    int s0 = csr[j];
    float c0 = ss ? ss[s0] : 1.f;
    short8 v0 = *(const short8*)(X + (size_t)s0 * 256 + c);
#pragma unroll
    for (int q = 0; q < 8; ++q) acc[q] += bf2f((u16)v0[q]) * c0;
  }
#pragma unroll
  for (int q = 0; q < 8; ++q) acc[q] += __shfl_xor(acc[q], 32, 64);
  if (part == 0){
    f32x4 f0 = {acc[0], acc[1], acc[2], acc[3]};
    f32x4 f1 = {acc[4], acc[5], acc[6], acc[7]};
    __builtin_nontemporal_store(f0, (f32x4*)(Pf + (size_t)wave * 256 + c));
    __builtin_nontemporal_store(f1, (f32x4*)(Pf + (size_t)wave * 256 + c + 4));
  }
}

// ====== gemmHG: H_b strip -> LDS fp32 -> G2 gemm (UNSCALED), per strip =====
__global__ __launch_bounds__(256) void gemmHG_kernel(
    const float* __restrict__ Pb,
    const u16* __restrict__ WH1b, const u16* __restrict__ WL1b,
    const float* __restrict__ b1b, const float* __restrict__ s_ib,
    const u16* __restrict__ WH2i, const u16* __restrict__ WL2i,
    u16* __restrict__ G12){
  __shared__ float Hs[16][260];
  int w = threadIdx.x >> 6;
  int lane = threadIdx.x & 63;
  int r16 = lane & 15, quad = lane >> 4;
  int m0 = blockIdx.x << 4;
  // ---- phase 1: H_b = relu((P_b@W1b)*s_ib + b1b) into LDS ----
  const float* aBase = Pb + (size_t)(m0 + r16) * 256 + quad * 8;
  short8 ah[8], al[8];
#pragma unroll
  for (int kt = 0; kt < 8; ++kt){
    float4 p0 = *(const float4*)(aBase + kt * 32);
    float4 p1 = *(const float4*)(aBase + kt * 32 + 4);
    float v[8] = {p0.x, p0.y, p0.z, p0.w, p1.x, p1.y, p1.z, p1.w};
    short8 h, l;
#pragma unroll
    for (int j = 0; j < 8; ++j){
      u16 hb = f2bf(v[j]);
      h[j] = (short)hb;
      l[j] = (short)f2bf(v[j] - bf2f(hb));
    }
    ah[kt] = h; al[kt] = l;
  }
  float rs1[4];
#pragma unroll
  for (int r = 0; r < 4; ++r) rs1[r] = s_ib[m0 + quad * 4 + r];
  for (int nt = w * 4; nt < w * 4 + 4; ++nt){
    f32x4 acc = {0.f, 0.f, 0.f, 0.f};
    const u16* bh = WH1b + ((size_t)nt * 64 + lane) * 8;
    const u16* bl = WL1b + ((size_t)nt * 64 + lane) * 8;
#pragma unroll
    for (int kt = 0; kt < 8; ++kt){
      short8 wh = *(const short8*)(bh + (size_t)kt * 16 * 512);
      short8 wl = *(const short8*)(bl + (size_t)kt * 16 * 512);
      acc = __builtin_amdgcn_mfma_f32_16x16x32_bf16(ah[kt], wh, acc, 0, 0, 0);
      acc = __builtin_amdgcn_mfma_f32_16x16x32_bf16(al[kt], wh, acc, 0, 0, 0);
      acc = __builtin_amdgcn_mfma_f32_16x16x32_bf16(ah[kt], wl, acc, 0, 0, 0);
    }
    int col = nt * 16 + r16;
    float bv = b1b[col];
#pragma unroll
    for (int r = 0; r < 4; ++r)
      Hs[quad * 4 + r][col] = fmaxf(acc[r] * rs1[r] + bv, 0.f);
  }
  __syncthreads();
  // ---- phase 2: G2 = H_b @ W2i (UNSCALED) -> G12 cols [256,384) ----
  short8 ah2[8], al2[8];
#pragma unroll
  for (int kt = 0; kt < 8; ++kt){
    float4 p0 = *(const float4*)&Hs[r16][kt * 32 + quad * 8];
    float4 p1 = *(const float4*)&Hs[r16][kt * 32 + quad * 8 + 4];
    float v[8] = {p0.x, p0.y, p0.z, p0.w, p1.x, p1.y, p1.z, p1.w};
    short8 h, l;
#pragma unroll
    for (int j = 0; j < 8; ++j){
      u16 hb = f2bf(v[j]);
      h[j] = (short)hb;
      l[j] = (short)f2bf(v[j] - bf2f(hb));
    }
    ah2[kt] = h; al2[kt] = l;
  }
  for (int nt = w * 2; nt < w * 2 + 2; ++nt){
    f32x4 acc = {0.f, 0.f, 0.f, 0.f};
    const u16* bh = WH2i + ((size_t)nt * 64 + lane) * 8;
    const u16* bl = WL2i + ((size_t)nt * 64 + lane) * 8;
#pragma unroll
    for (int kt = 0; kt < 8; ++kt){
      short8 wh = *(const short8*)(bh + (size_t)kt * 8 * 512);
      short8 wl = *(const short8*)(bl + (size_t)kt * 8 * 512);
      acc = __builtin_amdgcn_mfma_f32_16x16x32_bf16(ah2[kt], wh, acc, 0, 0, 0);
      acc = __builtin_amdgcn_mfma_f32_16x16x32_bf16(al2[kt], wh, acc, 0, 0, 0);
      acc = __builtin_amdgcn_mfma_f32_16x16x32_bf16(ah2[kt], wl, acc, 0, 0, 0);
    }
    int col = nt * 16 + r16;
#pragma unroll
    for (int r = 0; r < 4; ++r){
      u16 o = f2bf(acc[r]);
      __builtin_nontemporal_store(o, G12 + (size_t)(m0 + quad * 4 + r) * 384 + 256 + col);
    }
  }
}

// ============ merged inc aggregation (dst = A, 50000 rows) =================
// gather weight = s_oi[src] (G1/G2 stored unscaled); epilogues per segment.
__global__ __launch_bounds__(256) void agg_inc2_kernel(
    const u16* __restrict__ G12, const int* __restrict__ off,
    const int* __restrict__ csr, const float* __restrict__ s_oi,
    const float* __restrict__ s_ii, const float* __restrict__ s_ob,
    const float* __restrict__ b1i, const float* __restrict__ b2i,
    u16* __restrict__ Ha, float* __restrict__ outa){
  int wave = blockIdx.x * 4 + (threadIdx.x >> 6);
  int lane = threadIdx.x & 63;
  if (wave >= NA) return;
  int b0 = off[wave], b1 = off[wave + 1];
  int deg = b1 - b0;
  int c1 = lane * 4;
  int c2 = lane * 2;
  float acc[6];
#pragma unroll
  for (int q = 0; q < 6; ++q) acc[q] = 0.f;
  int idx = 0; float sc = 0.f;
  if (lane < deg){
    idx = csr[b0 + lane];
    sc = s_oi[idx];
  }
  int lim = deg < 64 ? deg : 64;
  for (int u = 0; u < lim; u += 4){
    ushort4 va[4]; ushort2 vb[4]; float w[4];
#pragma unroll
    for (int k = 0; k < 4; ++k){
      int e = u + k;
      int t = e < lim ? e : 0;
      int se = __shfl(idx, t, 64);
      float c0 = __shfl(sc, t, 64);
      w[k] = e < lim ? c0 : 0.f;
      const u16* r = G12 + (size_t)se * 384;
      va[k] = *(const ushort4*)(r + c1);
      vb[k] = *(const ushort2*)(r + 256 + c2);
    }
#pragma unroll
    for (int k = 0; k < 4; ++k){
      acc[0] += bf2f(va[k].x) * w[k];
      acc[1] += bf2f(va[k].y) * w[k];
      acc[2] += bf2f(va[k].z) * w[k];
      acc[3] += bf2f(va[k].w) * w[k];
      acc[4] += bf2f(vb[k].x) * w[k];
      acc[5] += bf2f(vb[k].y) * w[k];
    }
  }
  for (int j = b0 + 64; j < b1; ++j){
    int se = csr[j];
    float c0 = s_oi[se];
    const u16* r = G12 + (size_t)se * 384;
    ushort4 va = *(const ushort4*)(r + c1);
    ushort2 vb = *(const ushort2*)(r + 256 + c2);
    acc[0] += bf2f(va.x) * c0; acc[1] += bf2f(va.y) * c0;
    acc[2] += bf2f(va.z) * c0; acc[3] += bf2f(va.w) * c0;
    acc[4] += bf2f(vb.x) * c0; acc[5] += bf2f(vb.y) * c0;
  }
  float sii = s_ii[wave], sob = s_ob[wave];
  float4 bb1 = *(const float4*)(b1i + c1);
  f32x2 bb2 = *(const f32x2*)(b2i + c2);
  u16x4 o1;
  o1.x = f2bf(fmaxf(acc[0] * sii + bb1.x, 0.f) * sob);
  o1.y = f2bf(fmaxf(acc[1] * sii + bb1.y, 0.f) * sob);
  o1.z = f2bf(fmaxf(acc[2] * sii + bb1.z, 0.f) * sob);
  o1.w = f2bf(fmaxf(acc[3] * sii + bb1.w, 0.f) * sob);
  __builtin_nontemporal_store(o1, (u16x4*)(Ha + (size_t)wave * 256 + c1));
  f32x2 o2 = {acc[4] * sii + bb2.x, acc[5] * sii + bb2.y};
  __builtin_nontemporal_store(o2, (f32x2*)(outa + (size_t)wave * 128 + c2));
}

// ================= standalone GEMM (for out_b) =============================
__global__ __launch_bounds__(256) void gemm_kernel(
    const float* __restrict__ A,
    const u16* __restrict__ PWH, const u16* __restrict__ PWL,
    const float* __restrict__ bias, const float* __restrict__ rs,
    float* __restrict__ Cf, u16* __restrict__ C16,
    int M, int nT, int wpsShift, int doRelu, int ldC, int colOff){
  gemm_dev(blockIdx.x, A, PWH, PWL, bias, rs, Cf, C16,
           M, nT, wpsShift, doRelu, ldC, colOff);
}

extern "C" void kernel_launch(void* const* d_in, const int* in_sizes, int n_in,
                              void* d_out, int out_size, void* d_ws, size_t ws_size,
                              hipStream_t stream){
  const float* x_a = (const float*)d_in[0];
  const float* x_b = (const float*)d_in[1];
  const float* W1b = (const float*)d_in[2];
  const float* b1b = (const float*)d_in[3];
  const float* W1i = (const float*)d_in[4];
  const float* b1i = (const float*)d_in[5];
  const float* W2b = (const float*)d_in[6];
  const float* b2b = (const float*)d_in[7];
  const float* W2i = (const float*)d_in[8];
  const float* b2i = (const float*)d_in[9];
  const int* bs  = (const int*)d_in[10];
  const int* bd  = (const int*)d_in[11];
  const int* isc = (const int*)d_in[12];
  const int* idt = (const int*)d_in[13];

  char* w = (char*)d_ws;
  size_t o = 0;
  auto take = [&](size_t bytes) -> void* {
    void* p = w + o; o = (o + bytes + 255) & ~(size_t)255; return p;
  };
  // counters: c_bs[50000] | c_bd4[40000] | c_is4[40000] | c_id[50000]
  int* zint = (int*)take((size_t)180000 * sizeof(int));
  int* c_bs  = zint;
  int* c_bd4 = zint + 50000;
  int* c_is4 = zint + 90000;
  int* c_id  = zint + 130000;
  int* rank_bel = (int*)take(NE * sizeof(int));
  int* rank_inc = (int*)take(NE * sizeof(int));
  int* off_bel4 = (int*)take((40000 + 1) * sizeof(int));
  int* off_inc  = (int*)take((NA + 1) * sizeof(int));
  int* csr_bel = (int*)take(NE * sizeof(int));
  int* csr_inc = (int*)take(NE * sizeof(int));
  float* s_ob = (float*)take(NA * sizeof(float));
  float* s_ib = (float*)take(NB * sizeof(float));
  float* s_oi = (float*)take(NB * sizeof(float));
  float* s_ii = (float*)take(NA * sizeof(float));
  u16* pwh = (u16*)take(196608 * sizeof(u16));
  u16* pwl = (u16*)take(196608 * sizeof(u16));
  u16* pwh1b = pwh, *pwh1i = pwh + 65536, *pwh2b = pwh + 131072, *pwh2i = pwh + 163840;
  u16* pwl1b = pwl, *pwl1i = pwl + 65536, *pwl2b = pwl + 131072, *pwl2i = pwl + 163840;
  u16* xa16 = (u16*)take((size_t)NA * 256 * sizeof(u16));   // x_a bf16 (unscaled)
  u16* G12  = (u16*)take((size_t)NB * 384 * sizeof(u16));   // [G1 256 | G2 128] bf16
  u16* H_a  = (u16*)take((size_t)NA * 256 * sizeof(u16));   // relu(L1 inc)*s_ob, bf16
  float* P_b = (float*)take((size_t)NB * 256 * sizeof(float)); // bel agg out (reused)

  float* out_a = (float*)d_out;                     // [NA,128]
  float* out_b = (float*)d_out + (size_t)NA * 128;  // [NB,128]

  // ---- setup ----
  pre_kernel<<<256, 256, 0, stream>>>(zint, 180000 / 4, W1i, pwh, pwl);
  // [G1 gemm | hist+ranks | pack W1b/W2b/W2i | cvt x_a] in ONE dispatch
  mega_kernel<<<GB + HB + PB + CB, 256, 0, stream>>>(
      x_b, pwh1i, pwl1i, G12,
      bs, bd, isc, idt, c_bs, c_bd4, c_is4, c_id, rank_bel, rank_inc,
      W1b, W2b, W2i, pwh, pwl, x_a, xa16);
  scan_scales_kernel<<<52, 1024, 0, stream>>>(c_bs, c_bd4, c_is4, c_id,
                                              off_bel4, off_inc,
                                              s_ob, s_ib, s_oi, s_ii);
  fill_kernel<<<1172, 256, 0, stream>>>(bs, bd, isc, idt, rank_bel, rank_inc,
                                        off_bel4, off_inc, csr_bel, csr_inc);
  // ---- compute ----
  // P_b = agg_bel(xa16 * s_ob[src])
  agg_bel_kernel<<<2500, 256, 0, stream>>>(xa16, s_ob, off_bel4, csr_bel, P_b, NB);
  // H_b (LDS-only) = relu((P_b@W1b)*s_ib+b1b); G2 = H_b@W2i -> G12 cols 256..
  gemmHG_kernel<<<625, 256, 0, stream>>>(P_b, pwh1b, pwl1b, b1b, s_ib,
                                         pwh2i, pwl2i, G12);
  // merged inc agg (weight s_oi[src]): H_a (bf16, pre-scaled s_ob) + out_a
  agg_inc2_kernel<<<12500, 256, 0, stream>>>(G12, off_inc, csr_inc, s_oi,
                                             s_ii, s_ob, b1i, b2i, H_a, out_a);
  // P_b = agg_bel(H_a)  (H_a already src-scaled)
  agg_bel_kernel<<<2500, 256, 0, stream>>>(H_a, nullptr, off_bel4, csr_bel, P_b, NB);
  // out_b = (P_b@W2b)*s_ib + b2b
  gemm_kernel<<<625, 256, 0, stream>>>(P_b, pwh2b, pwl2b, b2b, s_ib,
                                       out_b, nullptr, NB, 8, 2, 0, 128, 0);
}